// Round 18
// baseline (106.294 us; speedup 1.0000x reference)
//
#include <hip/hip_runtime.h>
#include <hip/hip_bf16.h>
#include <math.h>

#define HIDDEN 512
#define NHEADS 8
#define HDIM 64
#define SLEN 2048
#define BATCH 4
#define NROWS (BATCH*SLEN)   /* 8192 */
#define RTAB (2*SLEN-1)      /* 4095 */
#define LOG2E 1.44269504088896340736f
#define SCALE_L2E (0.125f * LOG2E)

typedef _Float16 f16;
typedef f16 f16x8 __attribute__((ext_vector_type(8)));
typedef float f32x4 __attribute__((ext_vector_type(4)));
typedef unsigned short u16;
typedef unsigned int u32;
typedef u16 u16x4 __attribute__((ext_vector_type(4)));
typedef u16 u16x8 __attribute__((ext_vector_type(8)));
typedef u32 u32x4 __attribute__((ext_vector_type(4)));

// ---------------------------------------------------------------------------
// Kernel 1: relative-position bias biasrel[h][t-s+2047], pre-scaled by log2e.
// ---------------------------------------------------------------------------
__global__ __launch_bounds__(256) void bias_precompute(
    const float* __restrict__ bias_table, float* __restrict__ biasrel) {
  int i = blockIdx.x * 256 + threadIdx.x;
  if (i >= NHEADS * RTAB) return;
  int h = i / RTAB;
  int idx = i - h * RTAB;
  int rel = idx - (SLEN - 1);
  int ret = rel > 0 ? 16 : 0;
  int a = rel < 0 ? -rel : rel;
  int bidx;
  if (a < 8) {
    bidx = a;
  } else {
    float val = logf((float)a * 0.125f) / logf(16.0f) * 8.0f;
    bidx = 8 + (int)val;
    if (bidx > 15) bidx = 15;
  }
  biasrel[i] = bias_table[(ret + bidx) * NHEADS + h] * LOG2E;
}

// ---------------------------------------------------------------------------
// Kernel 2a: x f32 -> f16
// ---------------------------------------------------------------------------
__global__ __launch_bounds__(256) void conv_x(
    const float* __restrict__ x, u16* __restrict__ xh) {
  int i = blockIdx.x * 256 + threadIdx.x;
  const float4* p = (const float4*)(x + (size_t)i * 8);
  float4 a = p[0], b = p[1];
  u16x8 o;
  f16 t0 = (f16)a.x; o[0] = *(u16*)&t0;
  f16 t1 = (f16)a.y; o[1] = *(u16*)&t1;
  f16 t2 = (f16)a.z; o[2] = *(u16*)&t2;
  f16 t3 = (f16)a.w; o[3] = *(u16*)&t3;
  f16 t4 = (f16)b.x; o[4] = *(u16*)&t4;
  f16 t5 = (f16)b.y; o[5] = *(u16*)&t5;
  f16 t6 = (f16)b.z; o[6] = *(u16*)&t6;
  f16 t7 = (f16)b.w; o[7] = *(u16*)&t7;
  *(u16x8*)(xh + (size_t)i * 8) = o;
}

// ---------------------------------------------------------------------------
// Kernel 2b: weights f32 [k][n] -> f16 transposed [n][k].
// ---------------------------------------------------------------------------
__global__ __launch_bounds__(256) void conv_w(
    const float* __restrict__ Wq, const float* __restrict__ Wk,
    const float* __restrict__ Wv, const float* __restrict__ Wo,
    u16* __restrict__ Wt) {
  const float* W = blockIdx.y == 0 ? Wq : blockIdx.y == 1 ? Wk
                 : blockIdx.y == 2 ? Wv : Wo;
  u16* dst = Wt + (size_t)blockIdx.y * HIDDEN * HIDDEN;
  int t = blockIdx.x * 256 + threadIdx.x;
  int k = t >> 6, n0 = (t & 63) << 3;
  const float4* p = (const float4*)(W + (size_t)k * HIDDEN + n0);
  float4 a = p[0], b = p[1];
  float vals[8] = {a.x, a.y, a.z, a.w, b.x, b.y, b.z, b.w};
#pragma unroll
  for (int j = 0; j < 8; ++j) {
    f16 hv = (f16)vals[j];
    dst[(size_t)(n0 + j) * HIDDEN + k] = *(u16*)&hv;
  }
}

// ---------------------------------------------------------------------------
// Kernel 3: f16 MFMA GEMM, 64x128 tile (M x N), 4 waves as 1x4 (wave w owns
// n-cols [w*32, w*32+32)), BK=64, reg-staged dbuf. Grid (M/64, N/128, z).
// mode 0: f32 out (Wo). mode 1: z=0 (Q, scaled)/z=1 (K) -> f16 [B,H,S,D] via
// LDS-transpose; z=2 (V) -> f16 [B,H,D,S] sigma-permuted via LDS-transpose.
// ---------------------------------------------------------------------------
__global__ __launch_bounds__(256) void gemm_mfma(
    const u16* __restrict__ A, const u16* __restrict__ Wt0,
    const u16* __restrict__ Wt1, const u16* __restrict__ Wt2,
    void* __restrict__ O, int mode) {
  __shared__ u16 sm[192 * 72];             // As[64][72] | Bs[128][72]
  u16 (*As)[72] = (u16(*)[72])sm;
  u16 (*Bs)[72] = (u16(*)[72])(sm + 64 * 72);
  const u16* Wt = blockIdx.z == 0 ? Wt0 : blockIdx.z == 1 ? Wt1 : Wt2;
  const int tid = threadIdx.x;
  const int w = tid >> 6, l = tid & 63;
  const int lr = l & 15, lg = l >> 4;
  const int m0 = blockIdx.x << 6, n0 = blockIdx.y << 7;
  const int vtmode = (mode == 1) && (blockIdx.z == 2);

  f32x4 acc[4][2] = {};   // normal: [m-frag][n-frag]; vt: acc[j][i] = D[n_i][m_j]

  u16x8 areg[2], breg[4];
#pragma unroll
  for (int e = 0; e < 2; ++e) {
    int c = (e << 8) + tid;
    int row = c >> 3, g = c & 7;
    areg[e] = *(const u16x8*)(A + (size_t)(m0 + row) * HIDDEN + (g << 3));
  }
#pragma unroll
  for (int e = 0; e < 4; ++e) {
    int c = (e << 8) + tid;
    int row = c >> 3, g = c & 7;
    breg[e] = *(const u16x8*)(Wt + (size_t)(n0 + row) * HIDDEN + (g << 3));
  }

  for (int k0 = 0; k0 < HIDDEN; k0 += 64) {
    __syncthreads();
#pragma unroll
    for (int e = 0; e < 2; ++e) {
      int c = (e << 8) + tid;
      int row = c >> 3, g = c & 7;
      *(u16x8*)&As[row][g << 3] = areg[e];
    }
#pragma unroll
    for (int e = 0; e < 4; ++e) {
      int c = (e << 8) + tid;
      int row = c >> 3, g = c & 7;
      *(u16x8*)&Bs[row][g << 3] = breg[e];
    }
    __syncthreads();
    if (k0 + 64 < HIDDEN) {
#pragma unroll
      for (int e = 0; e < 2; ++e) {
        int c = (e << 8) + tid;
        int row = c >> 3, g = c & 7;
        areg[e] = *(const u16x8*)(A + (size_t)(m0 + row) * HIDDEN + k0 + 64 + (g << 3));
      }
#pragma unroll
      for (int e = 0; e < 4; ++e) {
        int c = (e << 8) + tid;
        int row = c >> 3, g = c & 7;
        breg[e] = *(const u16x8*)(Wt + (size_t)(n0 + row) * HIDDEN + k0 + 64 + (g << 3));
      }
    }
#pragma unroll
    for (int kk = 0; kk < 64; kk += 32) {
      f16x8 af[4], bf[2];
#pragma unroll
      for (int mt = 0; mt < 4; ++mt)
        af[mt] = *(const f16x8*)&As[(mt << 4) + lr][kk + (lg << 3)];
#pragma unroll
      for (int nt = 0; nt < 2; ++nt)
        bf[nt] = *(const f16x8*)&Bs[(w << 5) + (nt << 4) + lr][kk + (lg << 3)];
      if (!vtmode) {
#pragma unroll
        for (int mt = 0; mt < 4; ++mt)
#pragma unroll
          for (int nt = 0; nt < 2; ++nt)
            acc[mt][nt] = __builtin_amdgcn_mfma_f32_16x16x32_f16(
                af[mt], bf[nt], acc[mt][nt], 0, 0, 0);
      } else {
        // swapped: acc[j][i] = bf(i) x af(j) -> D[n-frag i][m-frag j]
#pragma unroll
        for (int i = 0; i < 2; ++i)
#pragma unroll
          for (int j = 0; j < 4; ++j)
            acc[j][i] = __builtin_amdgcn_mfma_f32_16x16x32_f16(
                bf[i], af[j], acc[j][i], 0, 0, 0);
      }
    }
  }

  if (mode == 0) {
    float* Of = (float*)O;
#pragma unroll
    for (int mt = 0; mt < 4; ++mt)
#pragma unroll
      for (int nt = 0; nt < 2; ++nt)
#pragma unroll
        for (int r = 0; r < 4; ++r) {
          int m = m0 + (mt << 4) + (lg << 2) + r;
          int n = n0 + (w << 5) + (nt << 4) + lr;
          Of[(size_t)m * HIDDEN + n] = acc[mt][nt][r];
        }
  } else if (!vtmode) {
    // Q/K: LDS transpose -> coalesced [B,H,S,D] u16x8 stores
    __syncthreads();
    u16* tt = sm;                           // [64][136]: [m_loc][n_loc]
    const float osc = (blockIdx.z == 0) ? SCALE_L2E : 1.0f;
#pragma unroll
    for (int mt = 0; mt < 4; ++mt)
#pragma unroll
      for (int nt = 0; nt < 2; ++nt)
#pragma unroll
        for (int r = 0; r < 4; ++r) {
          int ml = (mt << 4) + (lg << 2) + r;
          int nl = (w << 5) + (nt << 4) + lr;
          f16 hv = (f16)(acc[mt][nt][r] * osc);
          tt[ml * 136 + nl] = *(u16*)&hv;
        }
    __syncthreads();
    u16* O16 = (u16*)O + (size_t)blockIdx.z * NROWS * HIDDEN;
    int b = m0 >> 11, s0 = m0 & (SLEN - 1);
    int hl = tid >> 7, rr = tid & 127;
    int hh = (n0 >> 6) + hl;
    u16* obase = O16 + (((size_t)b * NHEADS + hh) * SLEN + s0) * HDIM;
#pragma unroll
    for (int c = 0; c < 4; ++c) {
      int sl = (rr >> 3) + (c << 4);
      int d8 = (rr & 7) << 3;
      u16x8 v = *(const u16x8*)&tt[sl * 136 + (hl << 6) + d8];
      *(u16x8*)(obase + (size_t)sl * HDIM + d8) = v;
    }
  } else {
    // V^T: LDS transpose -> coalesced sigma-permuted [B,H,D,S] stores
    __syncthreads();
    u16* tt = sm;                           // [128][72]: [n_loc][m_loc]
#pragma unroll
    for (int i = 0; i < 2; ++i)
#pragma unroll
      for (int j = 0; j < 4; ++j)
#pragma unroll
        for (int r = 0; r < 4; ++r) {
          int nl = (w << 5) + (i << 4) + (lg << 2) + r;
          int ml = (j << 4) + lr;
          f16 hv = (f16)acc[j][i][r];
          tt[nl * 72 + ml] = *(u16*)&hv;
        }
    __syncthreads();
    u16* O16 = (u16*)O + (size_t)2 * NROWS * HIDDEN;
    int nl = tid >> 1, half = tid & 1;
    int n = n0 + nl;
    int h = n >> 6, d = n & 63;
    int b = m0 >> 11, s_base = m0 & (SLEN - 1);
    u16* orow = O16 + (((size_t)b * NHEADS + h) * HDIM + d) * SLEN + s_base;
    const u16* trow = tt + nl * 72;
    // G[v] = V[p_inv(v)]; 4-runs: c0 = (v&~31)|(((v>>3)&3)<<2), c1 = c0+16
#pragma unroll
    for (int c = 0; c < 4; ++c) {
      int v_off = (half << 5) + (c << 3);
      int c0 = (v_off & ~31) | (((v_off >> 3) & 3) << 2);
      u16x4 lo = *(const u16x4*)(trow + c0);
      u16x4 hi = *(const u16x4*)(trow + c0 + 16);
      u16x8 st;
#pragma unroll
      for (int j = 0; j < 4; ++j) { st[j] = lo[j]; st[j + 4] = hi[j]; }
      *(u16x8*)(orow + v_off) = st;
    }
  }
}

// ---------------------------------------------------------------------------
// Kernel 4: flash attention (FROZEN, round-15): single-barrier LDS dbuf,
// no-max softmax, bias in MFMA C, far-tile const bias, swapped QK^T,
// sigma-permuted V^T b128 frags, l-via-ones-MFMA.
// ---------------------------------------------------------------------------
__global__ __launch_bounds__(256) void flash_attn_mfma(
    const u16* __restrict__ qg, const u16* __restrict__ kg,
    const u16* __restrict__ vtg, const float* __restrict__ biasrel,
    u16* __restrict__ attn_out) {
  __shared__ u16 Ks[2][64][72];   // [buf][kv][d]
  __shared__ u16 Vt[2][64][72];   // [buf][d][kv] (sigma-permuted kv)

  const int tid = threadIdx.x;
  const int w = tid >> 6, l = tid & 63;
  const int lr = l & 15, lg = l >> 4;

  int bid = blockIdx.x;
  int xcd = bid & 7, idx = bid >> 3;
  int bh = (xcd << 2) + (idx >> 4);
  int bx = idx & 15;
  int h = bh & 7, b = bh >> 3;
  int q0 = bx << 7;

  const u16* qp = qg + (size_t)bh * (SLEN * HDIM);
  const u16* kp = kg + (size_t)bh * (SLEN * HDIM);
  const u16* vp = vtg + (size_t)bh * (HDIM * SLEN);

  const float bias_pos = biasrel[h * RTAB + 2 * (SLEN - 1)];
  const float bias_neg = biasrel[h * RTAB];

  f16x8 aq[2][2];
#pragma unroll
  for (int sub = 0; sub < 2; ++sub) {
    const u16* qrow = qp + (size_t)(q0 + (w << 5) + (sub << 4) + lr) * HDIM + (lg << 3);
    aq[sub][0] = *(const f16x8*)(qrow);
    aq[sub][1] = *(const f16x8*)(qrow + 32);
  }

  const float* bb = biasrel + h * RTAB + (SLEN - 1) + (lg << 2) - lr - q0 - (w << 5);

  f32x4 acc[2][4] = {};
  f32x4 accl[2] = {};
  const f16x8 ones = {(f16)1.f, (f16)1.f, (f16)1.f, (f16)1.f,
                      (f16)1.f, (f16)1.f, (f16)1.f, (f16)1.f};

  u16x8 kreg[2], vreg[2];
#pragma unroll
  for (int e = 0; e < 2; ++e) {
    int c = tid + (e << 8);
    int row = c >> 3, c8 = (c & 7) << 3;
    kreg[e] = *(const u16x8*)(kp + (size_t)row * HDIM + c8);
    vreg[e] = *(const u16x8*)(vp + (size_t)row * SLEN + c8);
  }
#pragma unroll
  for (int e = 0; e < 2; ++e) {
    int c = tid + (e << 8);
    int row = c >> 3, c8 = (c & 7) << 3;
    *(u16x8*)&Ks[0][row][c8] = kreg[e];
    *(u16x8*)&Vt[0][row][c8] = vreg[e];
  }
#pragma unroll
  for (int e = 0; e < 2; ++e) {
    int c = tid + (e << 8);
    int row = c >> 3, c8 = (c & 7) << 3;
    kreg[e] = *(const u16x8*)(kp + (size_t)(64 + row) * HDIM + c8);
    vreg[e] = *(const u16x8*)(vp + (size_t)row * SLEN + 64 + c8);
  }
  __syncthreads();

  int cur = 0;
  for (int t0 = 0; t0 < SLEN; t0 += 64) {
    if (t0 + 64 < SLEN) {
#pragma unroll
      for (int e = 0; e < 2; ++e) {
        int c = tid + (e << 8);
        int row = c >> 3, c8 = (c & 7) << 3;
        *(u16x8*)&Ks[cur ^ 1][row][c8] = kreg[e];
        *(u16x8*)&Vt[cur ^ 1][row][c8] = vreg[e];
      }
      if (t0 + 128 < SLEN) {
#pragma unroll
        for (int e = 0; e < 2; ++e) {
          int c = tid + (e << 8);
          int row = c >> 3, c8 = (c & 7) << 3;
          kreg[e] = *(const u16x8*)(kp + (size_t)(t0 + 128 + row) * HDIM + c8);
          vreg[e] = *(const u16x8*)(vp + (size_t)row * SLEN + t0 + 128 + c8);
        }
      }
    }

    int dtq = t0 - q0;
    f32x4 sc[2][4];
    if (dtq >= 256 || dtq <= -192) {
      float c = (dtq > 0) ? bias_pos : bias_neg;
      f32x4 cv = {c, c, c, c};
#pragma unroll
      for (int sub = 0; sub < 2; ++sub)
#pragma unroll
        for (int ct = 0; ct < 4; ++ct) sc[sub][ct] = cv;
    } else {
#pragma unroll
      for (int sub = 0; sub < 2; ++sub)
#pragma unroll
        for (int ct = 0; ct < 4; ++ct)
#pragma unroll
          for (int r = 0; r < 4; ++r)
            sc[sub][ct][r] = bb[t0 + (ct << 4) + r - (sub << 4)];
    }

    f16x8 kf[4][2];
#pragma unroll
    for (int ct = 0; ct < 4; ++ct) {
      kf[ct][0] = *(const f16x8*)&Ks[cur][(ct << 4) + lr][lg << 3];
      kf[ct][1] = *(const f16x8*)&Ks[cur][(ct << 4) + lr][32 + (lg << 3)];
    }

    __builtin_amdgcn_s_setprio(1);
#pragma unroll
    for (int sub = 0; sub < 2; ++sub)
#pragma unroll
      for (int ct = 0; ct < 4; ++ct) {
        sc[sub][ct] = __builtin_amdgcn_mfma_f32_16x16x32_f16(
            kf[ct][0], aq[sub][0], sc[sub][ct], 0, 0, 0);
        sc[sub][ct] = __builtin_amdgcn_mfma_f32_16x16x32_f16(
            kf[ct][1], aq[sub][1], sc[sub][ct], 0, 0, 0);
      }
    __builtin_amdgcn_s_setprio(0);

#pragma unroll
    for (int sub = 0; sub < 2; ++sub)
#pragma unroll
      for (int ct = 0; ct < 4; ++ct)
#pragma unroll
        for (int r = 0; r < 4; ++r)
          sc[sub][ct][r] = __builtin_amdgcn_exp2f(sc[sub][ct][r]);

    f16x8 vf[2][4];
#pragma unroll
    for (int kb = 0; kb < 2; ++kb)
#pragma unroll
      for (int dt = 0; dt < 4; ++dt)
        vf[kb][dt] = *(const f16x8*)&Vt[cur][(dt << 4) + lr][(kb << 5) + (lg << 3)];

    __builtin_amdgcn_s_setprio(1);
#pragma unroll
    for (int sub = 0; sub < 2; ++sub)
#pragma unroll
      for (int kb = 0; kb < 2; ++kb) {
        u32 a0 = __builtin_bit_cast(u32,
            __builtin_amdgcn_cvt_pkrtz(sc[sub][2 * kb][0], sc[sub][2 * kb][1]));
        u32 a1 = __builtin_bit_cast(u32,
            __builtin_amdgcn_cvt_pkrtz(sc[sub][2 * kb][2], sc[sub][2 * kb][3]));
        u32 a2 = __builtin_bit_cast(u32,
            __builtin_amdgcn_cvt_pkrtz(sc[sub][2 * kb + 1][0], sc[sub][2 * kb + 1][1]));
        u32 a3 = __builtin_bit_cast(u32,
            __builtin_amdgcn_cvt_pkrtz(sc[sub][2 * kb + 1][2], sc[sub][2 * kb + 1][3]));
        u32x4 pk = {a0, a1, a2, a3};
        f16x8 pa = __builtin_bit_cast(f16x8, pk);
        accl[sub] = __builtin_amdgcn_mfma_f32_16x16x32_f16(
            pa, ones, accl[sub], 0, 0, 0);
#pragma unroll
        for (int dt = 0; dt < 4; ++dt)
          acc[sub][dt] = __builtin_amdgcn_mfma_f32_16x16x32_f16(
              pa, vf[kb][dt], acc[sub][dt], 0, 0, 0);
      }
    __builtin_amdgcn_s_setprio(0);

    __syncthreads();
    cur ^= 1;
  }

#pragma unroll
  for (int sub = 0; sub < 2; ++sub) {
    float linv[4];
#pragma unroll
    for (int r = 0; r < 4; ++r) linv[r] = 1.f / accl[sub][r];
    u16* op = attn_out +
              ((size_t)(b * SLEN) + q0 + (w << 5) + (sub << 4)) * HIDDEN + (h << 6);
#pragma unroll
    for (int r = 0; r < 4; ++r)
#pragma unroll
      for (int dt = 0; dt < 4; ++dt) {
        f16 hv = (f16)(acc[sub][dt][r] * linv[r]);
        op[(size_t)((lg << 2) + r) * HIDDEN + (dt << 4) + lr] = *(u16*)&hv;
      }
  }
}

// ---------------------------------------------------------------------------
extern "C" void kernel_launch(void* const* d_in, const int* in_sizes, int n_in,
                              void* d_out, int out_size, void* d_ws, size_t ws_size,
                              hipStream_t stream) {
  const float* x          = (const float*)d_in[0];
  const float* Wq         = (const float*)d_in[1];
  const float* Wk         = (const float*)d_in[2];
  const float* Wv         = (const float*)d_in[3];
  const float* Wo         = (const float*)d_in[4];
  const float* bias_table = (const float*)d_in[5];
  float* out = (float*)d_out;

  u16* xh   = (u16*)d_ws;                           // 8 MB f16 x
  u16* wt   = xh + (size_t)NROWS * HIDDEN;          // 2 MB (4 weights)
  u16* qkv  = wt + (size_t)4 * HIDDEN * HIDDEN;     // 24 MB
  u16* attno_h = qkv + (size_t)3 * NROWS * HIDDEN;  // 8 MB
  float* biasrel = (float*)(attno_h + (size_t)NROWS * HIDDEN);

  u16* qb = qkv;
  u16* kb = qkv + (size_t)NROWS * HIDDEN;
  u16* vb = qkv + (size_t)2 * NROWS * HIDDEN;   // [B,H,D,S] sigma-permuted

  bias_precompute<<<(NHEADS * RTAB + 255) / 256, 256, 0, stream>>>(bias_table, biasrel);
  conv_x<<<NROWS * HIDDEN / 8 / 256, 256, 0, stream>>>(x, xh);
  conv_w<<<dim3(HIDDEN * HIDDEN / 8 / 256, 4), 256, 0, stream>>>(Wq, Wk, Wv, Wo, wt);

  u16* wtq = wt;
  u16* wtk = wt + (size_t)HIDDEN * HIDDEN;
  u16* wtv = wt + (size_t)2 * HIDDEN * HIDDEN;
  u16* wto = wt + (size_t)3 * HIDDEN * HIDDEN;

  gemm_mfma<<<dim3(NROWS / 64, HIDDEN / 128, 3), 256, 0, stream>>>(
      xh, wtq, wtk, wtv, qkv, 1);

  flash_attn_mfma<<<SLEN / 128 * BATCH * NHEADS, 256, 0, stream>>>(
      qb, kb, vb, biasrel, attno_h);

  gemm_mfma<<<dim3(NROWS / 64, HIDDEN / 128, 1), 256, 0, stream>>>(
      attno_h, wto, wto, wto, out, 0);
}

// Round 19
// 100.588 us; speedup vs baseline: 1.0567x; 1.0567x over previous
//
#include <hip/hip_runtime.h>
#include <hip/hip_bf16.h>
#include <math.h>

#define HIDDEN 512
#define NHEADS 8
#define HDIM 64
#define SLEN 2048
#define BATCH 4
#define NROWS (BATCH*SLEN)   /* 8192 */
#define RTAB (2*SLEN-1)      /* 4095 */
#define LOG2E 1.44269504088896340736f
#define SCALE_L2E (0.125f * LOG2E)

typedef _Float16 f16;
typedef f16 f16x8 __attribute__((ext_vector_type(8)));
typedef float f32x4 __attribute__((ext_vector_type(4)));
typedef unsigned short u16;
typedef unsigned int u32;
typedef u16 u16x4 __attribute__((ext_vector_type(4)));
typedef u16 u16x8 __attribute__((ext_vector_type(8)));
typedef u32 u32x4 __attribute__((ext_vector_type(4)));

// ---------------------------------------------------------------------------
// Kernel 1: fused prep = conv_x (blocks 0..2047) | conv_w (2048..2559) |
// bias_precompute (2560..2687). One launch instead of three.
// ---------------------------------------------------------------------------
__global__ __launch_bounds__(256) void prep(
    const float* __restrict__ x, const float* __restrict__ Wq,
    const float* __restrict__ Wk, const float* __restrict__ Wv,
    const float* __restrict__ Wo, const float* __restrict__ bias_table,
    u16* __restrict__ xh, u16* __restrict__ Wt, float* __restrict__ biasrel) {
  int bid = blockIdx.x;
  int tid = threadIdx.x;
  if (bid < 2048) {
    // conv_x: x f32 -> f16
    int i = bid * 256 + tid;
    const float4* p = (const float4*)(x + (size_t)i * 8);
    float4 a = p[0], b = p[1];
    u16x8 o;
    f16 t0 = (f16)a.x; o[0] = *(u16*)&t0;
    f16 t1 = (f16)a.y; o[1] = *(u16*)&t1;
    f16 t2 = (f16)a.z; o[2] = *(u16*)&t2;
    f16 t3 = (f16)a.w; o[3] = *(u16*)&t3;
    f16 t4 = (f16)b.x; o[4] = *(u16*)&t4;
    f16 t5 = (f16)b.y; o[5] = *(u16*)&t5;
    f16 t6 = (f16)b.z; o[6] = *(u16*)&t6;
    f16 t7 = (f16)b.w; o[7] = *(u16*)&t7;
    *(u16x8*)(xh + (size_t)i * 8) = o;
  } else if (bid < 2560) {
    // conv_w: weights f32 [k][n] -> f16 transposed [n][k]
    int wb = bid - 2048;
    int wy = wb >> 7;
    const float* W = wy == 0 ? Wq : wy == 1 ? Wk : wy == 2 ? Wv : Wo;
    u16* dst = Wt + (size_t)wy * HIDDEN * HIDDEN;
    int t = (wb & 127) * 256 + tid;
    int k = t >> 6, n0 = (t & 63) << 3;
    const float4* p = (const float4*)(W + (size_t)k * HIDDEN + n0);
    float4 a = p[0], b = p[1];
    float vals[8] = {a.x, a.y, a.z, a.w, b.x, b.y, b.z, b.w};
#pragma unroll
    for (int j = 0; j < 8; ++j) {
      f16 hv = (f16)vals[j];
      dst[(size_t)(n0 + j) * HIDDEN + k] = *(u16*)&hv;
    }
  } else {
    // bias_precompute
    int i = (bid - 2560) * 256 + tid;
    if (i >= NHEADS * RTAB) return;
    int h = i / RTAB;
    int idx = i - h * RTAB;
    int rel = idx - (SLEN - 1);
    int ret = rel > 0 ? 16 : 0;
    int a = rel < 0 ? -rel : rel;
    int bidx;
    if (a < 8) {
      bidx = a;
    } else {
      float val = logf((float)a * 0.125f) / logf(16.0f) * 8.0f;
      bidx = 8 + (int)val;
      if (bidx > 15) bidx = 15;
    }
    biasrel[i] = bias_table[(ret + bidx) * NHEADS + h] * LOG2E;
  }
}

// ---------------------------------------------------------------------------
// Kernel 3: f16 MFMA GEMM (round-16 config: 128x128, reg-staged dbuf).
// mode 0: f32 out (Wo). mode 1: z=0 (Q, scaled)/z=1 (K) -> f16 [B,H,S,D] via
// LDS-transpose; z=2 (V) -> f16 [B,H,D,S] sigma-permuted via LDS-transpose.
// ---------------------------------------------------------------------------
__global__ __launch_bounds__(256) void gemm_mfma(
    const u16* __restrict__ A, const u16* __restrict__ Wt0,
    const u16* __restrict__ Wt1, const u16* __restrict__ Wt2,
    void* __restrict__ O, int mode) {
  __shared__ u16 sm[2 * 128 * 72];
  u16 (*As)[72] = (u16(*)[72])sm;
  u16 (*Bs)[72] = (u16(*)[72])(sm + 128 * 72);
  const u16* Wt = blockIdx.z == 0 ? Wt0 : blockIdx.z == 1 ? Wt1 : Wt2;
  const int tid = threadIdx.x;
  const int w = tid >> 6, l = tid & 63;
  const int lr = l & 15, lg = l >> 4;
  const int wr = w >> 1, wc = w & 1;
  const int m0 = blockIdx.x << 7, n0 = blockIdx.y << 7;
  const int vtmode = (mode == 1) && (blockIdx.z == 2);

  f32x4 acc[4][4] = {};

  u16x8 areg[4], breg[4];
#pragma unroll
  for (int e = 0; e < 4; ++e) {
    int c = (e << 8) + tid;
    int row = c >> 3, g = c & 7;
    areg[e] = *(const u16x8*)(A + (size_t)(m0 + row) * HIDDEN + (g << 3));
    breg[e] = *(const u16x8*)(Wt + (size_t)(n0 + row) * HIDDEN + (g << 3));
  }

  for (int k0 = 0; k0 < HIDDEN; k0 += 64) {
    __syncthreads();
#pragma unroll
    for (int e = 0; e < 4; ++e) {
      int c = (e << 8) + tid;
      int row = c >> 3, g = c & 7;
      *(u16x8*)&As[row][g << 3] = areg[e];
      *(u16x8*)&Bs[row][g << 3] = breg[e];
    }
    __syncthreads();
    if (k0 + 64 < HIDDEN) {
#pragma unroll
      for (int e = 0; e < 4; ++e) {
        int c = (e << 8) + tid;
        int row = c >> 3, g = c & 7;
        areg[e] = *(const u16x8*)(A + (size_t)(m0 + row) * HIDDEN + k0 + 64 + (g << 3));
        breg[e] = *(const u16x8*)(Wt + (size_t)(n0 + row) * HIDDEN + k0 + 64 + (g << 3));
      }
    }
#pragma unroll
    for (int kk = 0; kk < 64; kk += 32) {
      f16x8 af[4], bf[4];
#pragma unroll
      for (int mt = 0; mt < 4; ++mt)
        af[mt] = *(const f16x8*)&As[(wr << 6) + (mt << 4) + lr][kk + (lg << 3)];
#pragma unroll
      for (int nt = 0; nt < 4; ++nt)
        bf[nt] = *(const f16x8*)&Bs[(wc << 6) + (nt << 4) + lr][kk + (lg << 3)];
      if (!vtmode) {
#pragma unroll
        for (int mt = 0; mt < 4; ++mt)
#pragma unroll
          for (int nt = 0; nt < 4; ++nt)
            acc[mt][nt] = __builtin_amdgcn_mfma_f32_16x16x32_f16(
                af[mt], bf[nt], acc[mt][nt], 0, 0, 0);
      } else {
#pragma unroll
        for (int i = 0; i < 4; ++i)
#pragma unroll
          for (int j = 0; j < 4; ++j)
            acc[i][j] = __builtin_amdgcn_mfma_f32_16x16x32_f16(
                bf[i], af[j], acc[i][j], 0, 0, 0);
      }
    }
  }

  if (mode == 0) {
    float* Of = (float*)O;
#pragma unroll
    for (int mt = 0; mt < 4; ++mt)
#pragma unroll
      for (int nt = 0; nt < 4; ++nt)
#pragma unroll
        for (int r = 0; r < 4; ++r) {
          int m = m0 + (wr << 6) + (mt << 4) + (lg << 2) + r;
          int n = n0 + (wc << 6) + (nt << 4) + lr;
          Of[(size_t)m * HIDDEN + n] = acc[mt][nt][r];
        }
  } else if (!vtmode) {
    // Q/K: LDS transpose -> coalesced [B,H,S,D] u16x8 stores
    __syncthreads();
    u16* tt = sm;                           // [128][136]: [m_loc][n_loc]
    const float osc = (blockIdx.z == 0) ? SCALE_L2E : 1.0f;
#pragma unroll
    for (int mt = 0; mt < 4; ++mt)
#pragma unroll
      for (int nt = 0; nt < 4; ++nt)
#pragma unroll
        for (int r = 0; r < 4; ++r) {
          int ml = (wr << 6) + (mt << 4) + (lg << 2) + r;
          int nl = (wc << 6) + (nt << 4) + lr;
          f16 hv = (f16)(acc[mt][nt][r] * osc);
          tt[ml * 136 + nl] = *(u16*)&hv;
        }
    __syncthreads();
    u16* O16 = (u16*)O + (size_t)blockIdx.z * NROWS * HIDDEN;
    int b = m0 >> 11, s0 = m0 & (SLEN - 1);
    int hl = tid >> 7, rr = tid & 127;
    int hh = (n0 >> 6) + hl;
    u16* obase = O16 + (((size_t)b * NHEADS + hh) * SLEN + s0) * HDIM;
#pragma unroll
    for (int c = 0; c < 8; ++c) {
      int sl = (rr >> 3) + (c << 4);
      int d8 = (rr & 7) << 3;
      u16x8 v = *(const u16x8*)&tt[sl * 136 + (hl << 6) + d8];
      *(u16x8*)(obase + (size_t)sl * HDIM + d8) = v;
    }
  } else {
    __syncthreads();
    u16* tt = sm;                           // tile[128][136]: [n_loc][m_loc]
#pragma unroll
    for (int i = 0; i < 4; ++i)
#pragma unroll
      for (int j = 0; j < 4; ++j)
#pragma unroll
        for (int r = 0; r < 4; ++r) {
          int nl = (wc << 6) + (i << 4) + (lg << 2) + r;
          int ml = (wr << 6) + (j << 4) + lr;
          f16 hv = (f16)acc[i][j][r];
          tt[nl * 136 + ml] = *(u16*)&hv;
        }
    __syncthreads();
    u16* O16 = (u16*)O + (size_t)2 * NROWS * HIDDEN;
    int nl = tid >> 1, half = tid & 1;
    int n = n0 + nl;
    int h = n >> 6, d = n & 63;
    int b = m0 >> 11, s_base = m0 & (SLEN - 1);
    u16* orow = O16 + (((size_t)b * NHEADS + h) * HDIM + d) * SLEN + s_base;
    const u16* trow = tt + nl * 136;
#pragma unroll
    for (int c = 0; c < 8; ++c) {
      int v_off = (half << 6) + (c << 3);
      int c0 = (v_off & ~31) | (((v_off >> 3) & 3) << 2);
      u16x4 lo = *(const u16x4*)(trow + c0);
      u16x4 hi = *(const u16x4*)(trow + c0 + 16);
      u16x8 st;
#pragma unroll
      for (int j = 0; j < 4; ++j) { st[j] = lo[j]; st[j + 4] = hi[j]; }
      *(u16x8*)(orow + v_off) = st;
    }
  }
}

// ---------------------------------------------------------------------------
// Kernel 4: flash attention, KVBLK=128 (two 64-halves per barrier period).
// Single-barrier LDS dbuf (16 barriers total), no-max softmax, bias in MFMA C,
// far-tile const bias, swapped QK^T, sigma-permuted V^T b128 frags,
// l-via-ones-MFMA. Compute per half is byte-identical to round-15.
// ---------------------------------------------------------------------------
__global__ __launch_bounds__(256) void flash_attn_mfma(
    const u16* __restrict__ qg, const u16* __restrict__ kg,
    const u16* __restrict__ vtg, const float* __restrict__ biasrel,
    u16* __restrict__ attn_out) {
  __shared__ u16 Ks[2][128][72];   // [buf][kv][d]      36.9 KB
  __shared__ u16 Vt[2][64][136];   // [buf][d][kv]      34.8 KB

  const int tid = threadIdx.x;
  const int w = tid >> 6, l = tid & 63;
  const int lr = l & 15, lg = l >> 4;

  int bid = blockIdx.x;
  int xcd = bid & 7, idx = bid >> 3;
  int bh = (xcd << 2) + (idx >> 4);
  int bx = idx & 15;
  int h = bh & 7, b = bh >> 3;
  int q0 = bx << 7;

  const u16* qp = qg + (size_t)bh * (SLEN * HDIM);
  const u16* kp = kg + (size_t)bh * (SLEN * HDIM);
  const u16* vp = vtg + (size_t)bh * (HDIM * SLEN);

  const float bias_pos = biasrel[h * RTAB + 2 * (SLEN - 1)];
  const float bias_neg = biasrel[h * RTAB];

  f16x8 aq[2][2];
#pragma unroll
  for (int sub = 0; sub < 2; ++sub) {
    const u16* qrow = qp + (size_t)(q0 + (w << 5) + (sub << 4) + lr) * HDIM + (lg << 3);
    aq[sub][0] = *(const f16x8*)(qrow);
    aq[sub][1] = *(const f16x8*)(qrow + 32);
  }

  const float* bb = biasrel + h * RTAB + (SLEN - 1) + (lg << 2) - lr - q0 - (w << 5);

  f32x4 acc[2][4] = {};
  f32x4 accl[2] = {};
  const f16x8 ones = {(f16)1.f, (f16)1.f, (f16)1.f, (f16)1.f,
                      (f16)1.f, (f16)1.f, (f16)1.f, (f16)1.f};

  // staging: K = 128 rows x 64 d (4 chunks/thread); V = 64 d x 128 kv (4)
  u16x8 kreg[4], vreg[4];
#pragma unroll
  for (int e = 0; e < 4; ++e) {
    int c = tid + (e << 8);
    int krow = c >> 3, kc8 = (c & 7) << 3;
    kreg[e] = *(const u16x8*)(kp + (size_t)krow * HDIM + kc8);
    int vrow = c >> 4, vc8 = (c & 15) << 3;
    vreg[e] = *(const u16x8*)(vp + (size_t)vrow * SLEN + vc8);
  }
#pragma unroll
  for (int e = 0; e < 4; ++e) {
    int c = tid + (e << 8);
    int krow = c >> 3, kc8 = (c & 7) << 3;
    *(u16x8*)&Ks[0][krow][kc8] = kreg[e];
    int vrow = c >> 4, vc8 = (c & 15) << 3;
    *(u16x8*)&Vt[0][vrow][vc8] = vreg[e];
  }
#pragma unroll
  for (int e = 0; e < 4; ++e) {
    int c = tid + (e << 8);
    int krow = c >> 3, kc8 = (c & 7) << 3;
    kreg[e] = *(const u16x8*)(kp + (size_t)(128 + krow) * HDIM + kc8);
    int vrow = c >> 4, vc8 = (c & 15) << 3;
    vreg[e] = *(const u16x8*)(vp + (size_t)vrow * SLEN + 128 + vc8);
  }
  __syncthreads();

  int cur = 0;
  for (int t0 = 0; t0 < SLEN; t0 += 128) {
    // stage tile t+1 into buf[cur^1]; issue loads for tile t+2
    if (t0 + 128 < SLEN) {
#pragma unroll
      for (int e = 0; e < 4; ++e) {
        int c = tid + (e << 8);
        int krow = c >> 3, kc8 = (c & 7) << 3;
        *(u16x8*)&Ks[cur ^ 1][krow][kc8] = kreg[e];
        int vrow = c >> 4, vc8 = (c & 15) << 3;
        *(u16x8*)&Vt[cur ^ 1][vrow][vc8] = vreg[e];
      }
      if (t0 + 256 < SLEN) {
#pragma unroll
        for (int e = 0; e < 4; ++e) {
          int c = tid + (e << 8);
          int krow = c >> 3, kc8 = (c & 7) << 3;
          kreg[e] = *(const u16x8*)(kp + (size_t)(t0 + 256 + krow) * HDIM + kc8);
          int vrow = c >> 4, vc8 = (c & 15) << 3;
          vreg[e] = *(const u16x8*)(vp + (size_t)vrow * SLEN + t0 + 256 + vc8);
        }
      }
    }

#pragma unroll
    for (int hf = 0; hf < 2; ++hf) {
      const int kvb = hf << 6;             // kv base within the 128-tile
      int dtq = t0 + kvb - q0;
      f32x4 sc[2][4];
      if (dtq >= 256 || dtq <= -192) {
        float c = (dtq > 0) ? bias_pos : bias_neg;
        f32x4 cv = {c, c, c, c};
#pragma unroll
        for (int sub = 0; sub < 2; ++sub)
#pragma unroll
          for (int ct = 0; ct < 4; ++ct) sc[sub][ct] = cv;
      } else {
#pragma unroll
        for (int sub = 0; sub < 2; ++sub)
#pragma unroll
          for (int ct = 0; ct < 4; ++ct)
#pragma unroll
            for (int r = 0; r < 4; ++r)
              sc[sub][ct][r] = bb[t0 + kvb + (ct << 4) + r - (sub << 4)];
      }

      f16x8 kf[4][2];
#pragma unroll
      for (int ct = 0; ct < 4; ++ct) {
        kf[ct][0] = *(const f16x8*)&Ks[cur][kvb + (ct << 4) + lr][lg << 3];
        kf[ct][1] = *(const f16x8*)&Ks[cur][kvb + (ct << 4) + lr][32 + (lg << 3)];
      }

      __builtin_amdgcn_s_setprio(1);
#pragma unroll
      for (int sub = 0; sub < 2; ++sub)
#pragma unroll
        for (int ct = 0; ct < 4; ++ct) {
          sc[sub][ct] = __builtin_amdgcn_mfma_f32_16x16x32_f16(
              kf[ct][0], aq[sub][0], sc[sub][ct], 0, 0, 0);
          sc[sub][ct] = __builtin_amdgcn_mfma_f32_16x16x32_f16(
              kf[ct][1], aq[sub][1], sc[sub][ct], 0, 0, 0);
        }
      __builtin_amdgcn_s_setprio(0);

#pragma unroll
      for (int sub = 0; sub < 2; ++sub)
#pragma unroll
        for (int ct = 0; ct < 4; ++ct)
#pragma unroll
          for (int r = 0; r < 4; ++r)
            sc[sub][ct][r] = __builtin_amdgcn_exp2f(sc[sub][ct][r]);

      f16x8 vf[2][4];
#pragma unroll
      for (int kb = 0; kb < 2; ++kb)
#pragma unroll
        for (int dt = 0; dt < 4; ++dt)
          vf[kb][dt] = *(const f16x8*)&Vt[cur][(dt << 4) + lr][kvb + (kb << 5) + (lg << 3)];

      __builtin_amdgcn_s_setprio(1);
#pragma unroll
      for (int sub = 0; sub < 2; ++sub)
#pragma unroll
        for (int kb = 0; kb < 2; ++kb) {
          u32 a0 = __builtin_bit_cast(u32,
              __builtin_amdgcn_cvt_pkrtz(sc[sub][2 * kb][0], sc[sub][2 * kb][1]));
          u32 a1 = __builtin_bit_cast(u32,
              __builtin_amdgcn_cvt_pkrtz(sc[sub][2 * kb][2], sc[sub][2 * kb][3]));
          u32 a2 = __builtin_bit_cast(u32,
              __builtin_amdgcn_cvt_pkrtz(sc[sub][2 * kb + 1][0], sc[sub][2 * kb + 1][1]));
          u32 a3 = __builtin_bit_cast(u32,
              __builtin_amdgcn_cvt_pkrtz(sc[sub][2 * kb + 1][2], sc[sub][2 * kb + 1][3]));
          u32x4 pk = {a0, a1, a2, a3};
          f16x8 pa = __builtin_bit_cast(f16x8, pk);
          accl[sub] = __builtin_amdgcn_mfma_f32_16x16x32_f16(
              pa, ones, accl[sub], 0, 0, 0);
#pragma unroll
          for (int dt = 0; dt < 4; ++dt)
            acc[sub][dt] = __builtin_amdgcn_mfma_f32_16x16x32_f16(
                pa, vf[kb][dt], acc[sub][dt], 0, 0, 0);
        }
      __builtin_amdgcn_s_setprio(0);
    }

    __syncthreads();
    cur ^= 1;
  }

#pragma unroll
  for (int sub = 0; sub < 2; ++sub) {
    float linv[4];
#pragma unroll
    for (int r = 0; r < 4; ++r) linv[r] = 1.f / accl[sub][r];
    u16* op = attn_out +
              ((size_t)(b * SLEN) + q0 + (w << 5) + (sub << 4)) * HIDDEN + (h << 6);
#pragma unroll
    for (int r = 0; r < 4; ++r)
#pragma unroll
      for (int dt = 0; dt < 4; ++dt) {
        f16 hv = (f16)(acc[sub][dt][r] * linv[r]);
        op[(size_t)((lg << 2) + r) * HIDDEN + (dt << 4) + lr] = *(u16*)&hv;
      }
  }
}

// ---------------------------------------------------------------------------
extern "C" void kernel_launch(void* const* d_in, const int* in_sizes, int n_in,
                              void* d_out, int out_size, void* d_ws, size_t ws_size,
                              hipStream_t stream) {
  const float* x          = (const float*)d_in[0];
  const float* Wq         = (const float*)d_in[1];
  const float* Wk         = (const float*)d_in[2];
  const float* Wv         = (const float*)d_in[3];
  const float* Wo         = (const float*)d_in[4];
  const float* bias_table = (const float*)d_in[5];
  float* out = (float*)d_out;

  u16* xh   = (u16*)d_ws;                           // 8 MB f16 x
  u16* wt   = xh + (size_t)NROWS * HIDDEN;          // 2 MB (4 weights)
  u16* qkv  = wt + (size_t)4 * HIDDEN * HIDDEN;     // 24 MB
  u16* attno_h = qkv + (size_t)3 * NROWS * HIDDEN;  // 8 MB
  float* biasrel = (float*)(attno_h + (size_t)NROWS * HIDDEN);

  u16* qb = qkv;
  u16* kb = qkv + (size_t)NROWS * HIDDEN;
  u16* vb = qkv + (size_t)2 * NROWS * HIDDEN;   // [B,H,D,S] sigma-permuted

  prep<<<2688, 256, 0, stream>>>(x, Wq, Wk, Wv, Wo, bias_table, xh, wt, biasrel);

  u16* wtq = wt;
  u16* wtk = wt + (size_t)HIDDEN * HIDDEN;
  u16* wtv = wt + (size_t)2 * HIDDEN * HIDDEN;
  u16* wto = wt + (size_t)3 * HIDDEN * HIDDEN;

  gemm_mfma<<<dim3(NROWS / 128, HIDDEN / 128, 3), 256, 0, stream>>>(
      xh, wtq, wtk, wtv, qkv, 1);

  flash_attn_mfma<<<SLEN / 128 * BATCH * NHEADS, 256, 0, stream>>>(
      qb, kb, vb, biasrel, attno_h);

  gemm_mfma<<<dim3(NROWS / 128, HIDDEN / 128, 1), 256, 0, stream>>>(
      attno_h, wto, wto, wto, out, 0);
}